// Round 1
// baseline (1148.666 us; speedup 1.0000x reference)
//
#include <hip/hip_runtime.h>
#include <hip/hip_bf16.h>
#include <stdint.h>

// Problem constants (fixed by the reference).
constexpr int B_ = 8;
constexpr int S_ = 2048;
constexpr int K_ = 4096;
constexpr int M_ = 4096;

typedef __bf16 bf16x8 __attribute__((ext_vector_type(8)));
typedef float  f32x4  __attribute__((ext_vector_type(4)));

// 16B async global->LDS copy. LDS dest must be wave-uniform-base + lane*16.
__device__ __forceinline__ void async16(const void* g, void* l) {
  __builtin_amdgcn_global_load_lds(
      (__attribute__((address_space(1))) unsigned int*)(g),
      (__attribute__((address_space(3))) unsigned int*)(l),
      16, 0, 0);
}

// ---------------------------------------------------------------------------
// Mask format detection: the reference's bool mask may arrive as uint8 (1B),
// int32 (0/1) or float32 (0.0/1.0). Scan 16K words:
//   any word == 0x3F800000              -> float32 (flag 2)
//   any word with nonzero byte 1..3     -> uint8   (flag 1)
//   else                                -> int32   (flag 0)
// At 10% density the first 64KB decides this with certainty.
// ---------------------------------------------------------------------------
__global__ void detect_mask_kernel(const uint32_t* __restrict__ mw, int nwords,
                                   int* __restrict__ flag_out) {
  __shared__ int s_float, s_hi;
  if (threadIdx.x == 0) { s_float = 0; s_hi = 0; }
  __syncthreads();
  int f_float = 0, f_hi = 0;
  for (int i = threadIdx.x; i < nwords; i += blockDim.x) {
    uint32_t w = mw[i];
    if (w == 0x3F800000u) f_float = 1;
    else if (w & 0xFFFFFF00u) f_hi = 1;
  }
  if (f_float) atomicOr(&s_float, 1);
  if (f_hi)    atomicOr(&s_hi, 1);
  __syncthreads();
  if (threadIdx.x == 0) flag_out[0] = s_float ? 2 : (s_hi ? 1 : 0);
}

__device__ __forceinline__ bool mask_bit(const void* mask, int flag, size_t idx) {
  if (flag == 1) return ((const uint8_t*)mask)[idx] != 0;
  if (flag == 2) return ((const float*)mask)[idx] != 0.0f;
  return ((const int*)mask)[idx] != 0;
}

// Wb[m,k] = bf16( W[m,k] * mask[m,k] )
__global__ void build_wb_kernel(const float* __restrict__ w, const void* __restrict__ mask,
                                const int* __restrict__ flagp,
                                __hip_bfloat16* __restrict__ wb, int n) {
  const int flag = flagp[0];
  int idx = (blockIdx.x * blockDim.x + threadIdx.x) * 4;
  if (idx >= n) return;
  float4 v = *(const float4*)(w + idx);
  float m0, m1, m2, m3;
  if (flag == 1) {
    uchar4 mv = *(const uchar4*)((const uint8_t*)mask + idx);
    m0 = mv.x ? 1.f : 0.f; m1 = mv.y ? 1.f : 0.f;
    m2 = mv.z ? 1.f : 0.f; m3 = mv.w ? 1.f : 0.f;
  } else if (flag == 2) {
    float4 mv = *(const float4*)((const float*)mask + idx);
    m0 = mv.x != 0.f ? 1.f : 0.f; m1 = mv.y != 0.f ? 1.f : 0.f;
    m2 = mv.z != 0.f ? 1.f : 0.f; m3 = mv.w != 0.f ? 1.f : 0.f;
  } else {
    int4 mv = *(const int4*)((const int*)mask + idx);
    m0 = mv.x ? 1.f : 0.f; m1 = mv.y ? 1.f : 0.f;
    m2 = mv.z ? 1.f : 0.f; m3 = mv.w ? 1.f : 0.f;
  }
  union { ushort4 u4; __hip_bfloat16 h[4]; } o;
  o.h[0] = __float2bfloat16(v.x * m0);
  o.h[1] = __float2bfloat16(v.y * m1);
  o.h[2] = __float2bfloat16(v.z * m2);
  o.h[3] = __float2bfloat16(v.w * m3);
  *(ushort4*)(wb + idx) = o.u4;
}

// Xb = bf16(x)
__global__ void cvt_x_kernel(const float* __restrict__ x,
                             __hip_bfloat16* __restrict__ xb, int n) {
  int idx = (blockIdx.x * blockDim.x + threadIdx.x) * 4;
  if (idx >= n) return;
  float4 v = *(const float4*)(x + idx);
  union { ushort4 u4; __hip_bfloat16 h[4]; } o;
  o.h[0] = __float2bfloat16(v.x);
  o.h[1] = __float2bfloat16(v.y);
  o.h[2] = __float2bfloat16(v.z);
  o.h[3] = __float2bfloat16(v.w);
  *(ushort4*)(xb + idx) = o.u4;
}

// ---------------------------------------------------------------------------
// m97-style bf16 GEMM: C[b][m][s] = sum_k Wb[m][k] * Xb[b][s][k]
// 128x128 tile, BK=64, 256 threads = 4 waves (2x2), each wave 4x4 frags of
// mfma_f32_16x16x32_bf16. global_load_lds width=16 staging (lane-linear LDS,
// no padding allowed). C/D layout: col=lane&15, row=(lane>>4)*4+reg.
// ---------------------------------------------------------------------------
__global__ __launch_bounds__(256) void gemm_bt_kernel(
    const __hip_bfloat16* __restrict__ A,   // [M,K]
    const __hip_bfloat16* __restrict__ X,   // [B,S,K]
    float* __restrict__ C) {                // [B,M,S]
  constexpr int BM = 128, BN = 128, BK = 64;
  __shared__ __hip_bfloat16 sA[BM * BK];
  __shared__ __hip_bfloat16 sB[BN * BK];

  const int tid  = threadIdx.x;
  const int lane = tid & 63;
  const int wv   = tid >> 6;        // wave 0..3 -> 2x2 grid of 64x64
  const int wm   = (wv >> 1) * 64;
  const int wn   = (wv & 1) * 64;
  const int lr   = lane & 15;       // frag row (A: m, B: s)
  const int lq   = lane >> 4;       // quad -> k-chunk

  const size_t bm = (size_t)blockIdx.x * BM;
  const size_t bs = (size_t)blockIdx.y * BN;
  const size_t b  = blockIdx.z;

  const __hip_bfloat16* Ag = A + bm * K_;
  const __hip_bfloat16* Xg = X + b * (size_t)S_ * K_ + bs * K_;
  float* Cg = C + b * (size_t)M_ * S_ + bm * S_ + bs;

  const int srow = tid >> 3;        // 0..31 staging row
  const int scol = (tid & 7) * 8;   // staging col chunk (8 bf16 = 16B)

  f32x4 acc[4][4];
#pragma unroll
  for (int i = 0; i < 4; i++)
#pragma unroll
    for (int j = 0; j < 4; j++) acc[i][j] = f32x4{0.f, 0.f, 0.f, 0.f};

  for (int kt = 0; kt < K_; kt += BK) {
    if (kt) __syncthreads();   // prev compute done before overwriting LDS
#pragma unroll
    for (int i = 0; i < 4; ++i) {
      const int row = i * 32 + srow;
      async16(Ag + (size_t)row * K_ + kt + scol, &sA[row * BK + scol]);
      async16(Xg + (size_t)row * K_ + kt + scol, &sB[row * BK + scol]);
    }
    __syncthreads();           // drains vmcnt: staging visible

#pragma unroll
    for (int ks = 0; ks < BK; ks += 32) {
      bf16x8 af[4], bfr[4];
#pragma unroll
      for (int i = 0; i < 4; i++)
        af[i] = *(const bf16x8*)(const void*)&sA[(wm + i * 16 + lr) * BK + ks + lq * 8];
#pragma unroll
      for (int j = 0; j < 4; j++)
        bfr[j] = *(const bf16x8*)(const void*)&sB[(wn + j * 16 + lr) * BK + ks + lq * 8];
#pragma unroll
      for (int i = 0; i < 4; i++)
#pragma unroll
        for (int j = 0; j < 4; j++)
          acc[i][j] = __builtin_amdgcn_mfma_f32_16x16x32_bf16(af[i], bfr[j], acc[i][j], 0, 0, 0);
    }
  }

  // Epilogue: C[row][col], col=lane&15, row=(lane>>4)*4+r  [verified m89/m91]
#pragma unroll
  for (int i = 0; i < 4; i++) {
#pragma unroll
    for (int j = 0; j < 4; j++) {
      const int row = wm + i * 16 + lq * 4;
      const int col = wn + j * 16 + lr;
#pragma unroll
      for (int r = 0; r < 4; r++)
        Cg[(size_t)(row + r) * S_ + col] = acc[i][j][r];
    }
  }
}

// ---------------------------------------------------------------------------
// Fallback (only if ws_size too small for staging buffers): fp32 LDS-tiled.
// Correct but slow; expected never to run.
// ---------------------------------------------------------------------------
__global__ void fb_gemm_kernel(const float* __restrict__ x, const float* __restrict__ w,
                               const void* __restrict__ mask, const int* __restrict__ flagp,
                               float* __restrict__ out) {
  __shared__ float sW[16][17];
  __shared__ float sX[16][17];
  const int flag = flagp[0];
  const int tx = threadIdx.x, ty = threadIdx.y;
  const int m0 = blockIdx.x * 16, s0 = blockIdx.y * 16, b = blockIdx.z;
  float acc = 0.f;
  for (int kt = 0; kt < K_; kt += 16) {
    const size_t wi = (size_t)(m0 + ty) * K_ + kt + tx;
    sW[ty][tx] = mask_bit(mask, flag, wi) ? w[wi] : 0.f;
    sX[ty][tx] = x[(size_t)b * S_ * K_ + (size_t)(s0 + ty) * K_ + kt + tx];
    __syncthreads();
#pragma unroll
    for (int kk = 0; kk < 16; kk++) acc += sW[ty][kk] * sX[tx][kk];
    __syncthreads();
  }
  out[(size_t)b * M_ * S_ + (size_t)(m0 + ty) * S_ + s0 + tx] = acc;
}

extern "C" void kernel_launch(void* const* d_in, const int* in_sizes, int n_in,
                              void* d_out, int out_size, void* d_ws, size_t ws_size,
                              hipStream_t stream) {
  const float* x    = (const float*)d_in[0];
  const float* w    = (const float*)d_in[1];
  const void*  mask = d_in[2];
  float* out = (float*)d_out;

  uint8_t* ws = (uint8_t*)d_ws;
  int* flag = (int*)ws;
  const size_t offW = 256;
  const size_t offX = offW + (size_t)M_ * K_ * sizeof(__hip_bfloat16);
  const size_t need = offX + (size_t)B_ * S_ * K_ * sizeof(__hip_bfloat16);

  // Mask format detect (writes flag into ws; ws re-poisoned each call so
  // this must run every call — it does).
  detect_mask_kernel<<<1, 256, 0, stream>>>((const uint32_t*)mask, 16384, flag);

  if (ws_size >= need) {
    __hip_bfloat16* Wb = (__hip_bfloat16*)(ws + offW);
    __hip_bfloat16* Xb = (__hip_bfloat16*)(ws + offX);
    build_wb_kernel<<<(M_ * K_) / 1024, 256, 0, stream>>>(w, mask, flag, Wb, M_ * K_);
    cvt_x_kernel<<<(B_ * S_ * K_) / 1024, 256, 0, stream>>>(x, Xb, B_ * S_ * K_);
    dim3 grid(M_ / 128, S_ / 128, B_);
    gemm_bt_kernel<<<grid, 256, 0, stream>>>(Wb, Xb, out);
  } else {
    dim3 grid(M_ / 16, S_ / 16, B_);
    fb_gemm_kernel<<<grid, dim3(16, 16), 0, stream>>>(x, w, mask, flag, out);
  }
}